// Round 12
// baseline (154.633 us; speedup 1.0000x reference)
//
#include <hip/hip_runtime.h>
#include <math.h>

#define NC 10
#define NP 128
#define ND 512
#define GAMMA  0.1f
#define BCONST 10.0f
#define TAO    1.0f
#define LAMBDA 0.1f
#define THR2   1600.0f     // THRESHOLD^2 (compare d2 instead of sqrt(d2))
#define FEPS   1e-6f
#define NLDS   12          // fallback: proto slots 1..NLDS in LDS; slot 0 in regs; rest global
#define CH     16          // window size (one wave per window)
#define WPB    4           // waves per block
#define NBLK   131         // ceil((8192/16 + 10)/4)

__device__ __forceinline__ float allredf(float v) {
#pragma unroll
  for (int m = 1; m < 64; m <<= 1) v += __shfl_xor(v, m, 64);
  return v;
}

// ---------------------------------------------------------------------------
// K1: cheap compaction (byte-packed LDS labels, coalesced) + window sums.
// Blocks 0..3 publish the order list; block 0 publishes meta + resets state.
// ---------------------------------------------------------------------------
__global__ __launch_bounds__(256)
void sumc_kernel(const float* __restrict__ feats, const int* __restrict__ labels, int B,
                 float* __restrict__ chunksum, int* __restrict__ order_g,
                 int* __restrict__ cb_g, int* __restrict__ cc_g, int* __restrict__ chb_g,
                 int* __restrict__ ncht_g, int* __restrict__ done_g,
                 int* __restrict__ fail_g, int* __restrict__ nproto_g,
                 int* __restrict__ cdone_g, float* __restrict__ out)
{
  __shared__ unsigned int lab32[2048];   // B/4 packed labels (1 byte each)
  __shared__ int list[8192];
  __shared__ int wtot[4][NC];
  __shared__ int cb_s[NC], cc_s[NC], chb_s[NC];
  __shared__ int nchtot_s;

  const int t = threadIdx.x, lane = t & 63, w = t >> 6;

  // coalesced int4 label load -> byte-packed LDS
  const int4* lp = (const int4*)labels;
  for (int i = t; i < (B >> 2); i += 256) {
    int4 v = lp[i];
    lab32[i] = (unsigned)(v.x & 255) | ((unsigned)(v.y & 255) << 8)
             | ((unsigned)(v.z & 255) << 16) | ((unsigned)(v.w & 255) << 24);
  }
  __syncthreads();

  const int segsz = (B + 255) >> 8;
  const int i0 = t * segsz, i1 = min(i0 + segsz, B);

  int loc[NC];
#pragma unroll
  for (int c = 0; c < NC; ++c) loc[c] = 0;
  for (int i = i0; i < i1; ++i) {
    int l = (int)((lab32[i >> 2] >> ((i & 3) * 8)) & 255u);
#pragma unroll
    for (int c = 0; c < NC; ++c) loc[c] += (l == c);
  }
  int pre[NC];
#pragma unroll
  for (int c = 0; c < NC; ++c) pre[c] = loc[c];
#pragma unroll
  for (int m = 1; m < 64; m <<= 1) {
#pragma unroll
    for (int c = 0; c < NC; ++c) {
      int u = __shfl_up(pre[c], m, 64);
      if (lane >= m) pre[c] += u;
    }
  }
  if (lane == 63) {
#pragma unroll
    for (int c = 0; c < NC; ++c) wtot[w][c] = pre[c];
  }
  __syncthreads();

  int pos[NC];
  {
    int cb = 0, crun = 0;
#pragma unroll
    for (int c = 0; c < NC; ++c) {
      int tot = wtot[0][c] + wtot[1][c] + wtot[2][c] + wtot[3][c];
      int before = 0;
#pragma unroll
      for (int ww = 0; ww < 4; ++ww) before += (ww < w) ? wtot[ww][c] : 0;
      pos[c] = cb + before + (pre[c] - loc[c]);
      if (t == 0) { cb_s[c] = cb; cc_s[c] = tot; chb_s[c] = crun; }
      cb += tot;
      crun += (tot + CH - 1) / CH;
    }
    if (t == 0) nchtot_s = crun;
  }
  for (int i = i0; i < i1; ++i) {
    int l = (int)((lab32[i >> 2] >> ((i & 3) * 8)) & 255u);
#pragma unroll
    for (int c = 0; c < NC; ++c)
      if (l == c) list[pos[c]++] = i;
  }
  __syncthreads();

  // publish order (blocks 0..3, coalesced slices) + meta + resets (block 0)
  if (blockIdx.x < 4) {
    int q = (B + 3) >> 2;
    int lo = blockIdx.x * q, hi = min(lo + q, B);
    for (int i = lo + t; i < hi; i += 256) order_g[i] = list[i];
  }
  if (blockIdx.x == 0) {
    if (t < NC) {
      cb_g[t] = cb_s[t]; cc_g[t] = cc_s[t]; chb_g[t] = chb_s[t];
      done_g[t] = 0; fail_g[t] = 0; nproto_g[t] = 0;
    }
    if (t == 0) { ncht_g[0] = nchtot_s; cdone_g[0] = 0; out[0] = 0.f; }
  }

  const int gwid = blockIdx.x * WPB + w;
  if (gwid >= nchtot_s) return;

  int c = 0;
  while (c + 1 < NC && chb_s[c + 1] <= gwid) ++c;
  const int g = gwid - chb_s[c];
  const int cnt = cc_s[c], base = cb_s[c];
  const int k0 = g * CH, k1 = min(k0 + CH, cnt);

  float S[8] = {0, 0, 0, 0, 0, 0, 0, 0};
  int k = k0;
  for (; k + 4 <= k1; k += 4) {
    float4 A[4], Bv[4];
#pragma unroll
    for (int j = 0; j < 4; ++j) {
      int idx = list[base + k + j];
      const float4* fp = (const float4*)(feats + (size_t)idx * ND + lane * 8);
      A[j] = fp[0]; Bv[j] = fp[1];
    }
#pragma unroll
    for (int j = 0; j < 4; ++j) {
      S[0]+=A[j].x; S[1]+=A[j].y; S[2]+=A[j].z; S[3]+=A[j].w;
      S[4]+=Bv[j].x; S[5]+=Bv[j].y; S[6]+=Bv[j].z; S[7]+=Bv[j].w;
    }
  }
  for (; k < k1; ++k) {
    int idx = list[base + k];
    const float4* fp = (const float4*)(feats + (size_t)idx * ND + lane * 8);
    float4 a = fp[0], b = fp[1];
    S[0]+=a.x; S[1]+=a.y; S[2]+=a.z; S[3]+=a.w;
    S[4]+=b.x; S[5]+=b.y; S[6]+=b.z; S[7]+=b.w;
  }
  float4* cp = (float4*)(chunksum + (size_t)gwid * ND + lane * 8);
  cp[0] = make_float4(S[0], S[1], S[2], S[3]);
  cp[1] = make_float4(S[4], S[5], S[6], S[7]);
}

// ---------------------------------------------------------------------------
// K2: verify + finalize + fallback + (classes_done spin) + loss. One kernel.
// ---------------------------------------------------------------------------
__global__ __launch_bounds__(256)
void vloss_kernel(const float* __restrict__ feats, const int* __restrict__ labels, int B,
                  const float* __restrict__ chunksum, const int* __restrict__ order_g,
                  const int* __restrict__ cb_g, const int* __restrict__ cc_g,
                  const int* __restrict__ chb_g, const int* __restrict__ ncht_g,
                  int* __restrict__ done_g, int* __restrict__ fail_g,
                  float* __restrict__ gproto, float* __restrict__ p2s,
                  float* __restrict__ sps, int* __restrict__ nproto_g,
                  int* __restrict__ cdone_g, float* __restrict__ out)
{
  __shared__ int   cb_s[NC], cc_s[NC], chb_s[NC];
  __shared__ int   nchtot_s, target_s, fblock;
  __shared__ float ls_proto[NLDS][ND];
  __shared__ int   ls_cnt[NP];
  __shared__ float bsum[4];

  const int t = threadIdx.x, lane = t & 63, w = t >> 6;
  if (t < NC) { cb_s[t] = cb_g[t]; cc_s[t] = cc_g[t]; chb_s[t] = chb_g[t]; }
  if (t == 32) nchtot_s = ncht_g[0];
  if (t == 33) fblock = 0;
  __syncthreads();
  if (t == 0) {
    int tg = 0;
#pragma unroll
    for (int c = 0; c < NC; ++c) tg += (cc_s[c] > 0);
    target_s = tg;
  }
  __syncthreads();

  const int gwid = blockIdx.x * WPB + w;

  if (gwid < nchtot_s) {
    int c = 0;
    while (c + 1 < NC && chb_s[c + 1] <= gwid) ++c;
    const int g = gwid - chb_s[c];
    const int cnt = cc_s[c], base = cb_s[c];
    const int nchc = (cnt + CH - 1) / CH;
    const int k0 = g * CH, k1 = min(k0 + CH, cnt);
    int myidx = (lane < CH && k0 + lane < cnt) ? order_g[base + k0 + lane] : 0;

    // ---- prefix over preceding windows (ascending, 4-deep) ----
    float P[8] = {0, 0, 0, 0, 0, 0, 0, 0};
    {
      const float* cbase = chunksum + (size_t)chb_s[c] * ND + lane * 8;
      int j = 0;
      for (; j + 4 <= g; j += 4) {
        float4 A[4], Bv[4];
#pragma unroll
        for (int q = 0; q < 4; ++q) {
          const float4* pp = (const float4*)(cbase + (size_t)(j + q) * ND);
          A[q] = pp[0]; Bv[q] = pp[1];
        }
#pragma unroll
        for (int q = 0; q < 4; ++q) {
          P[0]+=A[q].x; P[1]+=A[q].y; P[2]+=A[q].z; P[3]+=A[q].w;
          P[4]+=Bv[q].x; P[5]+=Bv[q].y; P[6]+=Bv[q].z; P[7]+=Bv[q].w;
        }
      }
      for (; j < g; ++j) {
        const float4* pp = (const float4*)(cbase + (size_t)j * ND);
        float4 a = pp[0], b = pp[1];
        P[0]+=a.x; P[1]+=a.y; P[2]+=a.z; P[3]+=a.w;
        P[4]+=b.x; P[5]+=b.y; P[6]+=b.z; P[7]+=b.w;
      }
    }

    // ---- verify 16 samples (4-deep batch, batched butterfly) ----
    int k = k0;
    for (; k + 4 <= k1; k += 4) {
      float4 A[4], Bv[4];
#pragma unroll
      for (int j = 0; j < 4; ++j) {
        int idx = __shfl(myidx, k + j - k0, 64);
        const float4* fp = (const float4*)(feats + (size_t)idx * ND + lane * 8);
        A[j] = fp[0]; Bv[j] = fp[1];
      }
      float part[4];
#pragma unroll
      for (int j = 0; j < 4; ++j) {
        int kk = k + j;
        float f[8] = {A[j].x, A[j].y, A[j].z, A[j].w, Bv[j].x, Bv[j].y, Bv[j].z, Bv[j].w};
        if (kk > 0) {
          float invk = 1.f / (float)kk;
          float p = 0.f;
#pragma unroll
          for (int e = 0; e < 8; ++e) { float d = f[e] - P[e] * invk + FEPS; p += d * d; }
          part[j] = p;
        } else part[j] = 0.f;
#pragma unroll
        for (int e = 0; e < 8; ++e) P[e] += f[e];
      }
#pragma unroll
      for (int m = 1; m < 64; m <<= 1) {
#pragma unroll
        for (int j = 0; j < 4; ++j) part[j] += __shfl_xor(part[j], m, 64);
      }
      if (lane == 0) {
#pragma unroll
        for (int j = 0; j < 4; ++j) {
          int kk = k + j;
          if (kk > 0 && !(part[j] < THR2)) atomicOr(&fail_g[c], 1);
        }
      }
    }
    for (; k < k1; ++k) {
      int idx = __shfl(myidx, k - k0, 64);
      const float4* fp = (const float4*)(feats + (size_t)idx * ND + lane * 8);
      float4 fa = fp[0], fb = fp[1];
      float f[8] = {fa.x, fa.y, fa.z, fa.w, fb.x, fb.y, fb.z, fb.w};
      if (k > 0) {
        float invk = 1.f / (float)k;
        float p = 0.f;
#pragma unroll
        for (int e = 0; e < 8; ++e) { float d = f[e] - P[e] * invk + FEPS; p += d * d; }
        float d2 = allredf(p);
        if (!(d2 < THR2) && lane == 0) atomicOr(&fail_g[c], 1);
      }
#pragma unroll
      for (int e = 0; e < 8; ++e) P[e] += f[e];
    }

    // ---- last window holds full class sum: speculative finalize ----
    if (g == nchc - 1) {
      float invc = 1.f / (float)cnt;
      float p[8];
#pragma unroll
      for (int e = 0; e < 8; ++e) p[e] = P[e] * invc;
      float4* gp = (float4*)(gproto + (size_t)c * NP * ND + lane * 8);
      gp[0] = make_float4(p[0], p[1], p[2], p[3]);
      gp[1] = make_float4(p[4], p[5], p[6], p[7]);
      float P2p = 0.f, SPp = 0.f;
#pragma unroll
      for (int e = 0; e < 8; ++e) { P2p += p[e]*p[e]; SPp += p[e]; }
      float P2 = allredf(P2p), SP = allredf(SPp);
      if (lane == 0) { p2s[c*NP] = P2; sps[c*NP] = SP; nproto_g[c] = 1; }
    }

    // ---- done counting; last-arriver handles fallback + classes_done ----
    __threadfence();
    int old = 0;
    if (lane == 0)
      old = __hip_atomic_fetch_add(&done_g[c], 1, __ATOMIC_ACQ_REL, __HIP_MEMORY_SCOPE_AGENT);
    old = __shfl(old, 0, 64);
    if (old == nchc - 1) {
      int fv = 0;
      if (lane == 0) fv = atomicOr(&fail_g[c], 0);
      fv = __shfl(fv, 0, 64);
      if (fv) {
        if (lane == 0) { while (atomicCAS(&fblock, 0, 1) != 0) {} }
        // faithful sequential fallback (one wave; indices from global order)
        float p0[8];
        int cnt0 = 0, n = 0;
        float fA[8], fB[8], fC[8];

        auto LOADF = [&](float (&buf)[8], int m) {
          int idx = order_g[base + m];
          const float4* fp = (const float4*)(feats + (size_t)idx * ND + lane * 8);
          float4 a = fp[0], b = fp[1];
          buf[0]=a.x; buf[1]=a.y; buf[2]=a.z; buf[3]=a.w;
          buf[4]=b.x; buf[5]=b.y; buf[6]=b.z; buf[7]=b.w;
        };
        auto STEP = [&](float (&f)[8]) {
          float best = 3.4e38f;
          int bidx = 0;
          if (n > 0) {
            float part = 0.f;
#pragma unroll
            for (int e = 0; e < 8; ++e) { float d = f[e] - p0[e] + FEPS; part += d * d; }
            best = allredf(part);
            for (int j = 1; j < n; ++j) {
              float pj[8];
              if (j <= NLDS) {
                const float4* pp = (const float4*)(&ls_proto[j-1][lane*8]);
                float4 a = pp[0], b = pp[1];
                pj[0]=a.x; pj[1]=a.y; pj[2]=a.z; pj[3]=a.w;
                pj[4]=b.x; pj[5]=b.y; pj[6]=b.z; pj[7]=b.w;
              } else {
                const float4* pp = (const float4*)(gproto + ((size_t)c*NP + j)*ND + lane*8);
                float4 a = pp[0], b = pp[1];
                pj[0]=a.x; pj[1]=a.y; pj[2]=a.z; pj[3]=a.w;
                pj[4]=b.x; pj[5]=b.y; pj[6]=b.z; pj[7]=b.w;
              }
              float part2 = 0.f;
#pragma unroll
              for (int e = 0; e < 8; ++e) { float d = f[e] - pj[e] + FEPS; part2 += d * d; }
              float tot = allredf(part2);
              if (tot < best) { best = tot; bidx = j; }
            }
          }
          if (n > 0 && best < THR2) {
            if (bidx == 0) {
              float cc = (float)cnt0, iv = 1.f / (cc + 1.f);
#pragma unroll
              for (int e = 0; e < 8; ++e) p0[e] = (p0[e]*cc + f[e]) * iv;
              cnt0++;
            } else {
              int ci = ls_cnt[bidx];
              float cc = (float)ci, iv = 1.f / (cc + 1.f);
              if (bidx <= NLDS) {
                float* row = &ls_proto[bidx-1][lane*8];
#pragma unroll
                for (int e = 0; e < 8; ++e) row[e] = (row[e]*cc + f[e]) * iv;
              } else {
                float* row = gproto + ((size_t)c*NP + bidx)*ND + lane*8;
#pragma unroll
                for (int e = 0; e < 8; ++e) row[e] = (row[e]*cc + f[e]) * iv;
              }
              if (lane == 0) ls_cnt[bidx] = ci + 1;
            }
          } else {
            int app = min(n, NP - 1);
            if (app == 0) {
#pragma unroll
              for (int e = 0; e < 8; ++e) p0[e] = f[e];
              cnt0 = 1;
            } else if (app <= NLDS) {
              float* row = &ls_proto[app-1][lane*8];
#pragma unroll
              for (int e = 0; e < 8; ++e) row[e] = f[e];
              if (lane == 0) ls_cnt[app] = 1;
            } else {
              float* row = gproto + ((size_t)c*NP + app)*ND + lane*8;
#pragma unroll
              for (int e = 0; e < 8; ++e) row[e] = f[e];
              if (lane == 0) ls_cnt[app] = 1;
            }
            n = min(n + 1, NP);
          }
        };

        if (cnt > 0) LOADF(fA, 0);
        if (cnt > 1) LOADF(fB, 1);
        if (cnt > 2) LOADF(fC, 2);
        int m = 0;
        while (m < cnt) {
          STEP(fA); ++m; if (m + 2 < cnt) LOADF(fA, m + 2);
          if (m >= cnt) break;
          STEP(fB); ++m; if (m + 2 < cnt) LOADF(fB, m + 2);
          if (m >= cnt) break;
          STEP(fC); ++m; if (m + 2 < cnt) LOADF(fC, m + 2);
        }

        for (int j = 0; j < n; ++j) {
          float pj[8];
          if (j == 0) {
#pragma unroll
            for (int e = 0; e < 8; ++e) pj[e] = p0[e];
          } else if (j <= NLDS) {
            const float4* pp = (const float4*)(&ls_proto[j-1][lane*8]);
            float4 a = pp[0], b = pp[1];
            pj[0]=a.x; pj[1]=a.y; pj[2]=a.z; pj[3]=a.w;
            pj[4]=b.x; pj[5]=b.y; pj[6]=b.z; pj[7]=b.w;
          } else {
            const float4* pp = (const float4*)(gproto + ((size_t)c*NP + j)*ND + lane*8);
            float4 a = pp[0], b = pp[1];
            pj[0]=a.x; pj[1]=a.y; pj[2]=a.z; pj[3]=a.w;
            pj[4]=b.x; pj[5]=b.y; pj[6]=b.z; pj[7]=b.w;
          }
          float4* gp = (float4*)(gproto + ((size_t)c*NP + j)*ND + lane*8);
          gp[0] = make_float4(pj[0], pj[1], pj[2], pj[3]);
          gp[1] = make_float4(pj[4], pj[5], pj[6], pj[7]);
          float P2p = 0.f, SPp = 0.f;
#pragma unroll
          for (int e = 0; e < 8; ++e) { P2p += pj[e]*pj[e]; SPp += pj[e]; }
          float P2 = allredf(P2p), SP = allredf(SPp);
          if (lane == 0) { p2s[c*NP + j] = P2; sps[c*NP + j] = SP; }
        }
        if (lane == 0) nproto_g[c] = n;
        __threadfence_block();
        if (lane == 0) atomicExch(&fblock, 0);
      }
      __threadfence();
      if (lane == 0)
        __hip_atomic_fetch_add(cdone_g, 1, __ATOMIC_RELEASE, __HIP_MEMORY_SCOPE_AGENT);
    }
  }

  // ---- spin until all classes finalized (short; verify waves finish together) ----
  while (__hip_atomic_load(cdone_g, __ATOMIC_RELAXED, __HIP_MEMORY_SCOPE_AGENT) < target_s)
    __builtin_amdgcn_s_sleep(1);
  (void)__hip_atomic_load(cdone_g, __ATOMIC_ACQUIRE, __HIP_MEMORY_SCOPE_AGENT);

  // ---- loss phase: all waves, grid-stride over samples ----
  {
    const int NWTOT = gridDim.x * WPB;
    int np[NC];
    bool fast = true;
#pragma unroll
    for (int cc = 0; cc < NC; ++cc) { np[cc] = nproto_g[cc]; fast &= (np[cc] == 1); }

    float acc = 0.f;
    if (fast) {
      float p2v[NC], spv[NC];
#pragma unroll
      for (int cc = 0; cc < NC; ++cc) { p2v[cc] = p2s[cc*NP]; spv[cc] = sps[cc*NP]; }
      for (int b = gwid; b < B; b += NWTOT) {
        const float4* fp = (const float4*)(feats + (size_t)b * ND + lane * 8);
        float4 a4 = fp[0], b4 = fp[1];
        float f[8] = {a4.x, a4.y, a4.z, a4.w, b4.x, b4.y, b4.z, b4.w};
        int lab = labels[b];
        float v[12];
#pragma unroll
        for (int cc = 0; cc < NC; ++cc) {
          const float4* pp = (const float4*)(gproto + (size_t)cc * NP * ND + lane * 8);
          float4 pa = pp[0], pb = pp[1];
          v[cc] = f[0]*pa.x + f[1]*pa.y + f[2]*pa.z + f[3]*pa.w
                + f[4]*pb.x + f[5]*pb.y + f[6]*pb.z + f[7]*pb.w;
        }
        float f2p = 0.f, sfp = 0.f;
#pragma unroll
        for (int e = 0; e < 8; ++e) { f2p += f[e]*f[e]; sfp += f[e]; }
        v[10] = f2p; v[11] = sfp;
#pragma unroll
        for (int m = 1; m < 64; m <<= 1) {
#pragma unroll
          for (int q = 0; q < 12; ++q) v[q] += __shfl_xor(v[q], m, 64);
        }
        float f2 = v[10], sf = v[11];
        float one = 0.f, num = 0.f, pw = 0.f;
#pragma unroll
        for (int cc = 0; cc < NC; ++cc) {
          float d2 = f2 + p2v[cc] - 2.f*v[cc]
                   + 2.f*FEPS*(sf - spv[cc]) + (float)ND*FEPS*FEPS;
          d2 = fmaxf(d2, 0.f);
          float e = expf(-GAMMA * d2);
          one += e;
          if (cc == lab) num = e;
          float dmin = sqrtf(d2);
          float sign = (cc == lab) ? 1.f : -1.f;
          float z = BCONST - (TAO - dmin) * sign;
          float gg = (z > 10.f) ? z : log1pf(expf(z));
          pw += gg;
        }
        float prob = 1e-6f + ((one > 0.f) ? num / one : one);
        acc += -logf(prob) + LAMBDA * pw;
      }
    } else {
      for (int b = gwid; b < B; b += NWTOT) {
        const float4* fp = (const float4*)(feats + (size_t)b * ND + lane * 8);
        float4 a4 = fp[0], b4 = fp[1];
        float f[8] = {a4.x, a4.y, a4.z, a4.w, b4.x, b4.y, b4.z, b4.w};
        float f2p = 0.f, sfp = 0.f;
#pragma unroll
        for (int e = 0; e < 8; ++e) { f2p += f[e]*f[e]; sfp += f[e]; }
        float f2 = allredf(f2p);
        float sf = allredf(sfp);
        int lab = labels[b];
        float one = 0.f, num = 0.f, pw = 0.f;
        for (int cc = 0; cc < NC; ++cc) {
          int nn = np[cc];
          if (nn <= 0) continue;
          float sume = 0.f, bestd2 = 3.4e38f;
          for (int j = 0; j < nn; ++j) {
            const float4* pp = (const float4*)(gproto + ((size_t)cc*NP + j)*ND + lane*8);
            float4 pa = pp[0], pb = pp[1];
            float dp = f[0]*pa.x + f[1]*pa.y + f[2]*pa.z + f[3]*pa.w
                     + f[4]*pb.x + f[5]*pb.y + f[6]*pb.z + f[7]*pb.w;
            float dot = allredf(dp);
            float d2 = f2 + p2s[cc*NP + j] - 2.f*dot
                     + 2.f*FEPS*(sf - sps[cc*NP + j]) + (float)ND*FEPS*FEPS;
            d2 = fmaxf(d2, 0.f);
            sume  += expf(-GAMMA * d2);
            bestd2 = fminf(bestd2, d2);
          }
          one += sume;
          if (cc == lab) num = sume;
          float dmin = sqrtf(bestd2);
          float sign = (cc == lab) ? 1.f : -1.f;
          float z = BCONST - (TAO - dmin) * sign;
          float g = (z > 10.f) ? z : log1pf(expf(z));
          pw += g;
        }
        float prob = 1e-6f + ((one > 0.f) ? num / one : one);
        acc += -logf(prob) + LAMBDA * pw;
      }
    }

    if (lane == 0) bsum[w] = acc;
    __syncthreads();
    if (t == 0) atomicAdd(out, bsum[0] + bsum[1] + bsum[2] + bsum[3]);
  }
}

// ---------------------------------------------------------------------------
extern "C" void kernel_launch(void* const* d_in, const int* in_sizes, int n_in,
                              void* d_out, int out_size, void* d_ws, size_t ws_size,
                              hipStream_t stream) {
  const float* feats  = (const float*)d_in[0];
  const int*   labels = (const int*)d_in[1];
  int B = in_sizes[0] / ND;   // 8192
  const int maxwin = (B + CH - 1) / CH + NC;

  float* gproto   = (float*)d_ws;                          // NC*NP*ND
  float* p2s      = gproto + (size_t)NC * NP * ND;         // NC*NP
  float* sps      = p2s + NC * NP;                         // NC*NP
  float* chunksum = sps + NC * NP;                         // maxwin*ND
  int*   order_g  = (int*)(chunksum + (size_t)maxwin * ND);// B
  int*   cb_g     = order_g + B;                           // NC
  int*   cc_g     = cb_g + NC;                             // NC
  int*   chb_g    = cc_g + NC;                             // NC
  int*   ncht_g   = chb_g + NC;                            // 1
  int*   done_g   = ncht_g + 1;                            // NC
  int*   fail_g   = done_g + NC;                           // NC
  int*   nproto_g = fail_g + NC;                           // NC
  int*   cdone_g  = nproto_g + NC;                         // 1
  float* outf     = (float*)d_out;

  hipLaunchKernelGGL(sumc_kernel, dim3(NBLK), dim3(256), 0, stream,
                     feats, labels, B, chunksum, order_g, cb_g, cc_g, chb_g,
                     ncht_g, done_g, fail_g, nproto_g, cdone_g, outf);
  hipLaunchKernelGGL(vloss_kernel, dim3(NBLK), dim3(256), 0, stream,
                     feats, labels, B, chunksum, order_g, cb_g, cc_g, chb_g,
                     ncht_g, done_g, fail_g, gproto, p2s, sps, nproto_g,
                     cdone_g, outf);
}

// Round 13
// 79.278 us; speedup vs baseline: 1.9505x; 1.9505x over previous
//
#include <hip/hip_runtime.h>
#include <math.h>

#define NC 10
#define NP 128
#define ND 512
#define GAMMA  0.1f
#define BCONST 10.0f
#define TAO    1.0f
#define LAMBDA 0.1f
#define THR2   1600.0f     // THRESHOLD^2 (compare d2 instead of sqrt(d2))
#define FEPS   1e-6f
#define NLDS   12          // fallback: proto slots 1..NLDS in LDS; slot 0 in regs; rest global
#define CH     16          // window size (one wave per window)
#define WPB    2           // working waves per block (waves 2..3 exit early)
#define NBLK   261         // ceil((8192/16 + 10)/2) -> one block per CU

__device__ __forceinline__ float allredf(float v) {
#pragma unroll
  for (int m = 1; m < 64; m <<= 1) v += __shfl_xor(v, m, 64);
  return v;
}

// ---------------------------------------------------------------------------
// K1: cheap compaction (byte-packed LDS labels, coalesced) + window sums.
// Blocks 0..3 publish the order list; block 0 publishes meta + resets state.
// ---------------------------------------------------------------------------
__global__ __launch_bounds__(256)
void sumc_kernel(const float* __restrict__ feats, const int* __restrict__ labels, int B,
                 float* __restrict__ chunksum, int* __restrict__ order_g,
                 int* __restrict__ cb_g, int* __restrict__ cc_g, int* __restrict__ chb_g,
                 int* __restrict__ ncht_g, int* __restrict__ done_g,
                 int* __restrict__ fail_g, int* __restrict__ nproto_g,
                 float* __restrict__ out)
{
  __shared__ unsigned int lab32[2048];   // B/4 packed labels (1 byte each)
  __shared__ int list[8192];
  __shared__ int wtot[4][NC];
  __shared__ int cb_s[NC], cc_s[NC], chb_s[NC];
  __shared__ int nchtot_s;

  const int t = threadIdx.x, lane = t & 63, w = t >> 6;

  // coalesced int4 label load -> byte-packed LDS
  const int4* lp = (const int4*)labels;
  for (int i = t; i < (B >> 2); i += 256) {
    int4 v = lp[i];
    lab32[i] = (unsigned)(v.x & 255) | ((unsigned)(v.y & 255) << 8)
             | ((unsigned)(v.z & 255) << 16) | ((unsigned)(v.w & 255) << 24);
  }
  __syncthreads();

  const int segsz = (B + 255) >> 8;
  const int i0 = t * segsz, i1 = min(i0 + segsz, B);

  int loc[NC];
#pragma unroll
  for (int c = 0; c < NC; ++c) loc[c] = 0;
  for (int i = i0; i < i1; ++i) {
    int l = (int)((lab32[i >> 2] >> ((i & 3) * 8)) & 255u);
#pragma unroll
    for (int c = 0; c < NC; ++c) loc[c] += (l == c);
  }
  int pre[NC];
#pragma unroll
  for (int c = 0; c < NC; ++c) pre[c] = loc[c];
#pragma unroll
  for (int m = 1; m < 64; m <<= 1) {
#pragma unroll
    for (int c = 0; c < NC; ++c) {
      int u = __shfl_up(pre[c], m, 64);
      if (lane >= m) pre[c] += u;
    }
  }
  if (lane == 63) {
#pragma unroll
    for (int c = 0; c < NC; ++c) wtot[w][c] = pre[c];
  }
  __syncthreads();

  int pos[NC];
  {
    int cb = 0, crun = 0;
#pragma unroll
    for (int c = 0; c < NC; ++c) {
      int tot = wtot[0][c] + wtot[1][c] + wtot[2][c] + wtot[3][c];
      int before = 0;
#pragma unroll
      for (int ww = 0; ww < 4; ++ww) before += (ww < w) ? wtot[ww][c] : 0;
      pos[c] = cb + before + (pre[c] - loc[c]);
      if (t == 0) { cb_s[c] = cb; cc_s[c] = tot; chb_s[c] = crun; }
      cb += tot;
      crun += (tot + CH - 1) / CH;
    }
    if (t == 0) nchtot_s = crun;
  }
  for (int i = i0; i < i1; ++i) {
    int l = (int)((lab32[i >> 2] >> ((i & 3) * 8)) & 255u);
#pragma unroll
    for (int c = 0; c < NC; ++c)
      if (l == c) list[pos[c]++] = i;
  }
  __syncthreads();

  // publish order (blocks 0..3, coalesced slices) + meta + resets (block 0)
  if (blockIdx.x < 4) {
    int q = (B + 3) >> 2;
    int lo = blockIdx.x * q, hi = min(lo + q, B);
    for (int i = lo + t; i < hi; i += 256) order_g[i] = list[i];
  }
  if (blockIdx.x == 0) {
    if (t < NC) {
      cb_g[t] = cb_s[t]; cc_g[t] = cc_s[t]; chb_g[t] = chb_s[t];
      done_g[t] = 0; fail_g[t] = 0; nproto_g[t] = 0;
    }
    if (t == 0) { ncht_g[0] = nchtot_s; out[0] = 0.f; }
  }

  if (w >= WPB) return;
  const int gwid = blockIdx.x * WPB + w;
  if (gwid >= nchtot_s) return;

  int c = 0;
  while (c + 1 < NC && chb_s[c + 1] <= gwid) ++c;
  const int g = gwid - chb_s[c];
  const int cnt = cc_s[c], base = cb_s[c];
  const int k0 = g * CH, k1 = min(k0 + CH, cnt);

  float S[8] = {0, 0, 0, 0, 0, 0, 0, 0};
  int k = k0;
  for (; k + 8 <= k1; k += 8) {
    float4 A[8], Bv[8];
#pragma unroll
    for (int j = 0; j < 8; ++j) {
      int idx = list[base + k + j];
      const float4* fp = (const float4*)(feats + (size_t)idx * ND + lane * 8);
      A[j] = fp[0]; Bv[j] = fp[1];
    }
#pragma unroll
    for (int j = 0; j < 8; ++j) {
      S[0]+=A[j].x; S[1]+=A[j].y; S[2]+=A[j].z; S[3]+=A[j].w;
      S[4]+=Bv[j].x; S[5]+=Bv[j].y; S[6]+=Bv[j].z; S[7]+=Bv[j].w;
    }
  }
  for (; k < k1; ++k) {
    int idx = list[base + k];
    const float4* fp = (const float4*)(feats + (size_t)idx * ND + lane * 8);
    float4 a = fp[0], b = fp[1];
    S[0]+=a.x; S[1]+=a.y; S[2]+=a.z; S[3]+=a.w;
    S[4]+=b.x; S[5]+=b.y; S[6]+=b.z; S[7]+=b.w;
  }
  float4* cp = (float4*)(chunksum + (size_t)gwid * ND + lane * 8);
  cp[0] = make_float4(S[0], S[1], S[2], S[3]);
  cp[1] = make_float4(S[4], S[5], S[6], S[7]);
}

// ---------------------------------------------------------------------------
// K2: NO compaction. Reads meta + order from global (launch boundary
// guarantees visibility). Prefix + verify + speculative finalize +
// last-arriving-wave fallback. 8-deep memory pipelines.
// ---------------------------------------------------------------------------
__global__ __launch_bounds__(256)
void verify_kernel(const float* __restrict__ feats, int B,
                   const float* __restrict__ chunksum, const int* __restrict__ order_g,
                   const int* __restrict__ cb_g, const int* __restrict__ cc_g,
                   const int* __restrict__ chb_g, const int* __restrict__ ncht_g,
                   int* __restrict__ done_g, int* __restrict__ fail_g,
                   float* __restrict__ gproto, float* __restrict__ p2s,
                   float* __restrict__ sps, int* __restrict__ nproto_g)
{
  __shared__ int   cb_s[NC], cc_s[NC], chb_s[NC];
  __shared__ int   nchtot_s;
  __shared__ float ls_proto[NLDS][ND];
  __shared__ int   ls_cnt[NP];
  __shared__ int   fblock;

  const int t = threadIdx.x, lane = t & 63, w = t >> 6;
  if (t < NC) { cb_s[t] = cb_g[t]; cc_s[t] = cc_g[t]; chb_s[t] = chb_g[t]; }
  if (t == 32) nchtot_s = ncht_g[0];
  if (t == 33) fblock = 0;
  __syncthreads();

  if (w >= WPB) return;
  const int gwid = blockIdx.x * WPB + w;
  if (gwid >= nchtot_s) return;

  int c = 0;
  while (c + 1 < NC && chb_s[c + 1] <= gwid) ++c;
  const int g = gwid - chb_s[c];
  const int cnt = cc_s[c], base = cb_s[c];
  const int nchc = (cnt + CH - 1) / CH;
  const int k0 = g * CH, k1 = min(k0 + CH, cnt);
  int myidx = (lane < CH && k0 + lane < cnt) ? order_g[base + k0 + lane] : 0;

  // ---- prefix over preceding windows of this class (ascending, 8-deep) ----
  float P[8] = {0, 0, 0, 0, 0, 0, 0, 0};
  {
    const float* cbase = chunksum + (size_t)chb_s[c] * ND + lane * 8;
    int j = 0;
    for (; j + 8 <= g; j += 8) {
      float4 A[8], Bv[8];
#pragma unroll
      for (int q = 0; q < 8; ++q) {
        const float4* pp = (const float4*)(cbase + (size_t)(j + q) * ND);
        A[q] = pp[0]; Bv[q] = pp[1];
      }
#pragma unroll
      for (int q = 0; q < 8; ++q) {
        P[0]+=A[q].x; P[1]+=A[q].y; P[2]+=A[q].z; P[3]+=A[q].w;
        P[4]+=Bv[q].x; P[5]+=Bv[q].y; P[6]+=Bv[q].z; P[7]+=Bv[q].w;
      }
    }
    for (; j < g; ++j) {
      const float4* pp = (const float4*)(cbase + (size_t)j * ND);
      float4 a = pp[0], b = pp[1];
      P[0]+=a.x; P[1]+=a.y; P[2]+=a.z; P[3]+=a.w;
      P[4]+=b.x; P[5]+=b.y; P[6]+=b.z; P[7]+=b.w;
    }
  }

  // ---- verify 16 samples (8-deep batch, 8 interleaved butterflies) ----
  int k = k0;
  for (; k + 8 <= k1; k += 8) {
    float4 A[8], Bv[8];
#pragma unroll
    for (int j = 0; j < 8; ++j) {
      int idx = __shfl(myidx, k + j - k0, 64);
      const float4* fp = (const float4*)(feats + (size_t)idx * ND + lane * 8);
      A[j] = fp[0]; Bv[j] = fp[1];
    }
    float part[8];
#pragma unroll
    for (int j = 0; j < 8; ++j) {
      int kk = k + j;
      float f[8] = {A[j].x, A[j].y, A[j].z, A[j].w, Bv[j].x, Bv[j].y, Bv[j].z, Bv[j].w};
      if (kk > 0) {
        float invk = 1.f / (float)kk;
        float p = 0.f;
#pragma unroll
        for (int e = 0; e < 8; ++e) { float d = f[e] - P[e] * invk + FEPS; p += d * d; }
        part[j] = p;
      } else part[j] = 0.f;
#pragma unroll
      for (int e = 0; e < 8; ++e) P[e] += f[e];
    }
#pragma unroll
    for (int m = 1; m < 64; m <<= 1) {
#pragma unroll
      for (int j = 0; j < 8; ++j) part[j] += __shfl_xor(part[j], m, 64);
    }
    if (lane == 0) {
#pragma unroll
      for (int j = 0; j < 8; ++j) {
        int kk = k + j;
        if (kk > 0 && !(part[j] < THR2)) atomicOr(&fail_g[c], 1);
      }
    }
  }
  for (; k < k1; ++k) {
    int idx = __shfl(myidx, k - k0, 64);
    const float4* fp = (const float4*)(feats + (size_t)idx * ND + lane * 8);
    float4 fa = fp[0], fb = fp[1];
    float f[8] = {fa.x, fa.y, fa.z, fa.w, fb.x, fb.y, fb.z, fb.w};
    if (k > 0) {
      float invk = 1.f / (float)k;
      float p = 0.f;
#pragma unroll
      for (int e = 0; e < 8; ++e) { float d = f[e] - P[e] * invk + FEPS; p += d * d; }
      float d2 = allredf(p);
      if (!(d2 < THR2) && lane == 0) atomicOr(&fail_g[c], 1);
    }
#pragma unroll
    for (int e = 0; e < 8; ++e) P[e] += f[e];
  }

  // ---- last window holds the full class sum: speculative finalize ----
  if (g == nchc - 1) {
    float invc = 1.f / (float)cnt;
    float p[8];
#pragma unroll
    for (int e = 0; e < 8; ++e) p[e] = P[e] * invc;
    float4* gp = (float4*)(gproto + (size_t)c * NP * ND + lane * 8);
    gp[0] = make_float4(p[0], p[1], p[2], p[3]);
    gp[1] = make_float4(p[4], p[5], p[6], p[7]);
    float P2p = 0.f, SPp = 0.f;
#pragma unroll
    for (int e = 0; e < 8; ++e) { P2p += p[e]*p[e]; SPp += p[e]; }
    float P2 = allredf(P2p), SP = allredf(SPp);
    if (lane == 0) { p2s[c*NP] = P2; sps[c*NP] = SP; nproto_g[c] = 1; }
  }

  // ---- last-arriving wave for class c: run fallback if speculation failed ----
  __threadfence();
  int old = 0;
  if (lane == 0) old = atomicAdd(&done_g[c], 1);
  old = __shfl(old, 0, 64);
  if (old != nchc - 1) return;
  __threadfence();
  int fv = 0;
  if (lane == 0) fv = atomicOr(&fail_g[c], 0);   // atomic load
  fv = __shfl(fv, 0, 64);
  if (!fv) return;

  if (lane == 0) { while (atomicCAS(&fblock, 0, 1) != 0) {} }  // block LDS lock

  // faithful sequential fallback (one wave; indices from global order)
  {
    float p0[8];
    int cnt0 = 0, n = 0;
    float fA[8], fB[8], fC[8];

    auto LOADF = [&](float (&buf)[8], int m) {
      int idx = order_g[base + m];
      const float4* fp = (const float4*)(feats + (size_t)idx * ND + lane * 8);
      float4 a = fp[0], b = fp[1];
      buf[0]=a.x; buf[1]=a.y; buf[2]=a.z; buf[3]=a.w;
      buf[4]=b.x; buf[5]=b.y; buf[6]=b.z; buf[7]=b.w;
    };
    auto STEP = [&](float (&f)[8]) {
      float best = 3.4e38f;
      int bidx = 0;
      if (n > 0) {
        float part = 0.f;
#pragma unroll
        for (int e = 0; e < 8; ++e) { float d = f[e] - p0[e] + FEPS; part += d * d; }
        best = allredf(part);
        for (int j = 1; j < n; ++j) {
          float pj[8];
          if (j <= NLDS) {
            const float4* pp = (const float4*)(&ls_proto[j-1][lane*8]);
            float4 a = pp[0], b = pp[1];
            pj[0]=a.x; pj[1]=a.y; pj[2]=a.z; pj[3]=a.w;
            pj[4]=b.x; pj[5]=b.y; pj[6]=b.z; pj[7]=b.w;
          } else {
            const float4* pp = (const float4*)(gproto + ((size_t)c*NP + j)*ND + lane*8);
            float4 a = pp[0], b = pp[1];
            pj[0]=a.x; pj[1]=a.y; pj[2]=a.z; pj[3]=a.w;
            pj[4]=b.x; pj[5]=b.y; pj[6]=b.z; pj[7]=b.w;
          }
          float part2 = 0.f;
#pragma unroll
          for (int e = 0; e < 8; ++e) { float d = f[e] - pj[e] + FEPS; part2 += d * d; }
          float tot = allredf(part2);
          if (tot < best) { best = tot; bidx = j; }
        }
      }
      if (n > 0 && best < THR2) {
        if (bidx == 0) {
          float cc = (float)cnt0, iv = 1.f / (cc + 1.f);
#pragma unroll
          for (int e = 0; e < 8; ++e) p0[e] = (p0[e]*cc + f[e]) * iv;
          cnt0++;
        } else {
          int ci = ls_cnt[bidx];
          float cc = (float)ci, iv = 1.f / (cc + 1.f);
          if (bidx <= NLDS) {
            float* row = &ls_proto[bidx-1][lane*8];
#pragma unroll
            for (int e = 0; e < 8; ++e) row[e] = (row[e]*cc + f[e]) * iv;
          } else {
            float* row = gproto + ((size_t)c*NP + bidx)*ND + lane*8;
#pragma unroll
            for (int e = 0; e < 8; ++e) row[e] = (row[e]*cc + f[e]) * iv;
          }
          if (lane == 0) ls_cnt[bidx] = ci + 1;
        }
      } else {
        int app = min(n, NP - 1);
        if (app == 0) {
#pragma unroll
          for (int e = 0; e < 8; ++e) p0[e] = f[e];
          cnt0 = 1;
        } else if (app <= NLDS) {
          float* row = &ls_proto[app-1][lane*8];
#pragma unroll
          for (int e = 0; e < 8; ++e) row[e] = f[e];
          if (lane == 0) ls_cnt[app] = 1;
        } else {
          float* row = gproto + ((size_t)c*NP + app)*ND + lane*8;
#pragma unroll
          for (int e = 0; e < 8; ++e) row[e] = f[e];
          if (lane == 0) ls_cnt[app] = 1;
        }
        n = min(n + 1, NP);
      }
    };

    if (cnt > 0) LOADF(fA, 0);
    if (cnt > 1) LOADF(fB, 1);
    if (cnt > 2) LOADF(fC, 2);
    int m = 0;
    while (m < cnt) {
      STEP(fA); ++m; if (m + 2 < cnt) LOADF(fA, m + 2);
      if (m >= cnt) break;
      STEP(fB); ++m; if (m + 2 < cnt) LOADF(fB, m + 2);
      if (m >= cnt) break;
      STEP(fC); ++m; if (m + 2 < cnt) LOADF(fC, m + 2);
    }

    for (int j = 0; j < n; ++j) {
      float pj[8];
      if (j == 0) {
#pragma unroll
        for (int e = 0; e < 8; ++e) pj[e] = p0[e];
      } else if (j <= NLDS) {
        const float4* pp = (const float4*)(&ls_proto[j-1][lane*8]);
        float4 a = pp[0], b = pp[1];
        pj[0]=a.x; pj[1]=a.y; pj[2]=a.z; pj[3]=a.w;
        pj[4]=b.x; pj[5]=b.y; pj[6]=b.z; pj[7]=b.w;
      } else {
        const float4* pp = (const float4*)(gproto + ((size_t)c*NP + j)*ND + lane*8);
        float4 a = pp[0], b = pp[1];
        pj[0]=a.x; pj[1]=a.y; pj[2]=a.z; pj[3]=a.w;
        pj[4]=b.x; pj[5]=b.y; pj[6]=b.z; pj[7]=b.w;
      }
      float4* gp = (float4*)(gproto + ((size_t)c*NP + j)*ND + lane*8);
      gp[0] = make_float4(pj[0], pj[1], pj[2], pj[3]);
      gp[1] = make_float4(pj[4], pj[5], pj[6], pj[7]);
      float P2p = 0.f, SPp = 0.f;
#pragma unroll
      for (int e = 0; e < 8; ++e) { P2p += pj[e]*pj[e]; SPp += pj[e]; }
      float P2 = allredf(P2p), SP = allredf(SPp);
      if (lane == 0) { p2s[c*NP + j] = P2; sps[c*NP + j] = SP; }
    }
    if (lane == 0) nproto_g[c] = n;
  }

  __threadfence_block();
  if (lane == 0) atomicExch(&fblock, 0);
}

// ---------------------------------------------------------------------------
// K3: loss. One wave per sample; fast path = one batched 12-value butterfly.
// ---------------------------------------------------------------------------
__global__ __launch_bounds__(256)
void loss_kernel(const float* __restrict__ feats, const int* __restrict__ labels, int B,
                 const float* __restrict__ gproto, const float* __restrict__ p2s,
                 const float* __restrict__ sps, const int* __restrict__ nproto_g,
                 float* __restrict__ out)
{
  __shared__ float bsum[4];
  const int lane = threadIdx.x & 63;
  const int wid  = threadIdx.x >> 6;
  const int gw   = blockIdx.x * 4 + wid;
  const int nw   = gridDim.x * 4;

  int np[NC];
  bool fast = true;
#pragma unroll
  for (int cc = 0; cc < NC; ++cc) { np[cc] = nproto_g[cc]; fast &= (np[cc] == 1); }

  float acc = 0.f;
  if (fast) {
    float p2v[NC], spv[NC];
#pragma unroll
    for (int cc = 0; cc < NC; ++cc) { p2v[cc] = p2s[cc*NP]; spv[cc] = sps[cc*NP]; }
    for (int b = gw; b < B; b += nw) {
      const float4* fp = (const float4*)(feats + (size_t)b * ND + lane * 8);
      float4 a4 = fp[0], b4 = fp[1];
      float f[8] = {a4.x, a4.y, a4.z, a4.w, b4.x, b4.y, b4.z, b4.w};
      int lab = labels[b];
      float v[12];
#pragma unroll
      for (int cc = 0; cc < NC; ++cc) {
        const float4* pp = (const float4*)(gproto + (size_t)cc * NP * ND + lane * 8);
        float4 pa = pp[0], pb = pp[1];
        v[cc] = f[0]*pa.x + f[1]*pa.y + f[2]*pa.z + f[3]*pa.w
              + f[4]*pb.x + f[5]*pb.y + f[6]*pb.z + f[7]*pb.w;
      }
      float f2p = 0.f, sfp = 0.f;
#pragma unroll
      for (int e = 0; e < 8; ++e) { f2p += f[e]*f[e]; sfp += f[e]; }
      v[10] = f2p; v[11] = sfp;
#pragma unroll
      for (int m = 1; m < 64; m <<= 1) {
#pragma unroll
        for (int q = 0; q < 12; ++q) v[q] += __shfl_xor(v[q], m, 64);
      }
      float f2 = v[10], sf = v[11];
      float one = 0.f, num = 0.f, pw = 0.f;
#pragma unroll
      for (int cc = 0; cc < NC; ++cc) {
        float d2 = f2 + p2v[cc] - 2.f*v[cc]
                 + 2.f*FEPS*(sf - spv[cc]) + (float)ND*FEPS*FEPS;
        d2 = fmaxf(d2, 0.f);
        float e = expf(-GAMMA * d2);
        one += e;
        if (cc == lab) num = e;
        float dmin = sqrtf(d2);
        float sign = (cc == lab) ? 1.f : -1.f;
        float z = BCONST - (TAO - dmin) * sign;
        float gg = (z > 10.f) ? z : log1pf(expf(z));
        pw += gg;
      }
      float prob = 1e-6f + ((one > 0.f) ? num / one : one);
      acc += -logf(prob) + LAMBDA * pw;
    }
  } else {
    for (int b = gw; b < B; b += nw) {
      const float4* fp = (const float4*)(feats + (size_t)b * ND + lane * 8);
      float4 a4 = fp[0], b4 = fp[1];
      float f[8] = {a4.x, a4.y, a4.z, a4.w, b4.x, b4.y, b4.z, b4.w};
      float f2p = 0.f, sfp = 0.f;
#pragma unroll
      for (int e = 0; e < 8; ++e) { f2p += f[e]*f[e]; sfp += f[e]; }
      float f2 = allredf(f2p);
      float sf = allredf(sfp);
      int lab = labels[b];
      float one = 0.f, num = 0.f, pw = 0.f;
      for (int cc = 0; cc < NC; ++cc) {
        int nn = np[cc];
        if (nn <= 0) continue;
        float sume = 0.f, bestd2 = 3.4e38f;
        for (int j = 0; j < nn; ++j) {
          const float4* pp = (const float4*)(gproto + ((size_t)cc*NP + j)*ND + lane*8);
          float4 pa = pp[0], pb = pp[1];
          float dp = f[0]*pa.x + f[1]*pa.y + f[2]*pa.z + f[3]*pa.w
                   + f[4]*pb.x + f[5]*pb.y + f[6]*pb.z + f[7]*pb.w;
          float dot = allredf(dp);
          float d2 = f2 + p2s[cc*NP + j] - 2.f*dot
                   + 2.f*FEPS*(sf - sps[cc*NP + j]) + (float)ND*FEPS*FEPS;
          d2 = fmaxf(d2, 0.f);
          sume  += expf(-GAMMA * d2);
          bestd2 = fminf(bestd2, d2);
        }
        one += sume;
        if (cc == lab) num = sume;
        float dmin = sqrtf(bestd2);
        float sign = (cc == lab) ? 1.f : -1.f;
        float z = BCONST - (TAO - dmin) * sign;
        float g = (z > 10.f) ? z : log1pf(expf(z));
        pw += g;
      }
      float prob = 1e-6f + ((one > 0.f) ? num / one : one);
      acc += -logf(prob) + LAMBDA * pw;
    }
  }

  if (lane == 0) bsum[wid] = acc;
  __syncthreads();
  if (threadIdx.x == 0) atomicAdd(out, bsum[0] + bsum[1] + bsum[2] + bsum[3]);
}

// ---------------------------------------------------------------------------
extern "C" void kernel_launch(void* const* d_in, const int* in_sizes, int n_in,
                              void* d_out, int out_size, void* d_ws, size_t ws_size,
                              hipStream_t stream) {
  const float* feats  = (const float*)d_in[0];
  const int*   labels = (const int*)d_in[1];
  int B = in_sizes[0] / ND;   // 8192
  const int maxwin = (B + CH - 1) / CH + NC;

  float* gproto   = (float*)d_ws;                          // NC*NP*ND
  float* p2s      = gproto + (size_t)NC * NP * ND;         // NC*NP
  float* sps      = p2s + NC * NP;                         // NC*NP
  float* chunksum = sps + NC * NP;                         // maxwin*ND
  int*   order_g  = (int*)(chunksum + (size_t)maxwin * ND);// B
  int*   cb_g     = order_g + B;                           // NC
  int*   cc_g     = cb_g + NC;                             // NC
  int*   chb_g    = cc_g + NC;                             // NC
  int*   ncht_g   = chb_g + NC;                            // 1
  int*   done_g   = ncht_g + 1;                            // NC
  int*   fail_g   = done_g + NC;                           // NC
  int*   nproto_g = fail_g + NC;                           // NC
  float* outf     = (float*)d_out;

  hipLaunchKernelGGL(sumc_kernel, dim3(NBLK), dim3(256), 0, stream,
                     feats, labels, B, chunksum, order_g, cb_g, cc_g, chb_g,
                     ncht_g, done_g, fail_g, nproto_g, outf);
  hipLaunchKernelGGL(verify_kernel, dim3(NBLK), dim3(256), 0, stream,
                     feats, B, chunksum, order_g, cb_g, cc_g, chb_g, ncht_g,
                     done_g, fail_g, gproto, p2s, sps, nproto_g);
  hipLaunchKernelGGL(loss_kernel, dim3(2048), dim3(256), 0, stream,
                     feats, labels, B, gproto, p2s, sps, nproto_g, outf);
}

// Round 14
// 78.261 us; speedup vs baseline: 1.9759x; 1.0130x over previous
//
#include <hip/hip_runtime.h>
#include <math.h>

#define NC 10
#define NP 128
#define ND 512
#define GAMMA  0.1f
#define BCONST 10.0f
#define TAO    1.0f
#define LAMBDA 0.1f
#define THR2   1600.0f     // THRESHOLD^2 (compare d2 instead of sqrt(d2))
#define FEPS   1e-6f
#define NLDS   12          // fallback: proto slots 1..NLDS in LDS; slot 0 in regs; rest global
#define CH     16          // window size (one wave per window)
#define WPB    2           // working waves per block (waves 2..3 exit early)
#define NBLK   261         // ceil((8192/16 + 10)/2) -> one block per CU

__device__ __forceinline__ float allredf(float v) {
#pragma unroll
  for (int m = 1; m < 64; m <<= 1) v += __shfl_xor(v, m, 64);
  return v;
}

// ---------------------------------------------------------------------------
// K1: cheap compaction (byte-packed LDS labels, coalesced) + window sums.
// Blocks 0..3 publish the order list; block 0 publishes meta + resets state.
// ---------------------------------------------------------------------------
__global__ __launch_bounds__(256)
void sumc_kernel(const float* __restrict__ feats, const int* __restrict__ labels, int B,
                 float* __restrict__ chunksum, int* __restrict__ order_g,
                 int* __restrict__ cb_g, int* __restrict__ cc_g, int* __restrict__ chb_g,
                 int* __restrict__ ncht_g, int* __restrict__ done_g,
                 int* __restrict__ fail_g, int* __restrict__ nproto_g,
                 float* __restrict__ out)
{
  __shared__ unsigned int lab32[2048];   // B/4 packed labels (1 byte each)
  __shared__ int list[8192];
  __shared__ int wtot[4][NC];
  __shared__ int cb_s[NC], cc_s[NC], chb_s[NC];
  __shared__ int nchtot_s;

  const int t = threadIdx.x, lane = t & 63, w = t >> 6;

  // coalesced int4 label load -> byte-packed LDS
  const int4* lp = (const int4*)labels;
  for (int i = t; i < (B >> 2); i += 256) {
    int4 v = lp[i];
    lab32[i] = (unsigned)(v.x & 255) | ((unsigned)(v.y & 255) << 8)
             | ((unsigned)(v.z & 255) << 16) | ((unsigned)(v.w & 255) << 24);
  }
  __syncthreads();

  const int segsz = (B + 255) >> 8;
  const int i0 = t * segsz, i1 = min(i0 + segsz, B);

  int loc[NC];
#pragma unroll
  for (int c = 0; c < NC; ++c) loc[c] = 0;
  for (int i = i0; i < i1; ++i) {
    int l = (int)((lab32[i >> 2] >> ((i & 3) * 8)) & 255u);
#pragma unroll
    for (int c = 0; c < NC; ++c) loc[c] += (l == c);
  }
  int pre[NC];
#pragma unroll
  for (int c = 0; c < NC; ++c) pre[c] = loc[c];
#pragma unroll
  for (int m = 1; m < 64; m <<= 1) {
#pragma unroll
    for (int c = 0; c < NC; ++c) {
      int u = __shfl_up(pre[c], m, 64);
      if (lane >= m) pre[c] += u;
    }
  }
  if (lane == 63) {
#pragma unroll
    for (int c = 0; c < NC; ++c) wtot[w][c] = pre[c];
  }
  __syncthreads();

  int pos[NC];
  {
    int cb = 0, crun = 0;
#pragma unroll
    for (int c = 0; c < NC; ++c) {
      int tot = wtot[0][c] + wtot[1][c] + wtot[2][c] + wtot[3][c];
      int before = 0;
#pragma unroll
      for (int ww = 0; ww < 4; ++ww) before += (ww < w) ? wtot[ww][c] : 0;
      pos[c] = cb + before + (pre[c] - loc[c]);
      if (t == 0) { cb_s[c] = cb; cc_s[c] = tot; chb_s[c] = crun; }
      cb += tot;
      crun += (tot + CH - 1) / CH;
    }
    if (t == 0) nchtot_s = crun;
  }
  for (int i = i0; i < i1; ++i) {
    int l = (int)((lab32[i >> 2] >> ((i & 3) * 8)) & 255u);
#pragma unroll
    for (int c = 0; c < NC; ++c)
      if (l == c) list[pos[c]++] = i;
  }
  __syncthreads();

  // publish order (blocks 0..3, coalesced slices) + meta + resets (block 0)
  if (blockIdx.x < 4) {
    int q = (B + 3) >> 2;
    int lo = blockIdx.x * q, hi = min(lo + q, B);
    for (int i = lo + t; i < hi; i += 256) order_g[i] = list[i];
  }
  if (blockIdx.x == 0) {
    if (t < NC) {
      cb_g[t] = cb_s[t]; cc_g[t] = cc_s[t]; chb_g[t] = chb_s[t];
      done_g[t] = 0; fail_g[t] = 0; nproto_g[t] = 0;
    }
    if (t == 0) { ncht_g[0] = nchtot_s; out[0] = 0.f; }
  }

  if (w >= WPB) return;
  const int gwid = blockIdx.x * WPB + w;
  if (gwid >= nchtot_s) return;

  int c = 0;
  while (c + 1 < NC && chb_s[c + 1] <= gwid) ++c;
  const int g = gwid - chb_s[c];
  const int cnt = cc_s[c], base = cb_s[c];
  const int k0 = g * CH, k1 = min(k0 + CH, cnt);

  float S[8] = {0, 0, 0, 0, 0, 0, 0, 0};
  int k = k0;
  for (; k + 8 <= k1; k += 8) {
    float4 A[8], Bv[8];
#pragma unroll
    for (int j = 0; j < 8; ++j) {
      int idx = list[base + k + j];
      const float4* fp = (const float4*)(feats + (size_t)idx * ND + lane * 8);
      A[j] = fp[0]; Bv[j] = fp[1];
    }
#pragma unroll
    for (int j = 0; j < 8; ++j) {
      S[0]+=A[j].x; S[1]+=A[j].y; S[2]+=A[j].z; S[3]+=A[j].w;
      S[4]+=Bv[j].x; S[5]+=Bv[j].y; S[6]+=Bv[j].z; S[7]+=Bv[j].w;
    }
  }
  for (; k < k1; ++k) {
    int idx = list[base + k];
    const float4* fp = (const float4*)(feats + (size_t)idx * ND + lane * 8);
    float4 a = fp[0], b = fp[1];
    S[0]+=a.x; S[1]+=a.y; S[2]+=a.z; S[3]+=a.w;
    S[4]+=b.x; S[5]+=b.y; S[6]+=b.z; S[7]+=b.w;
  }
  float4* cp = (float4*)(chunksum + (size_t)gwid * ND + lane * 8);
  cp[0] = make_float4(S[0], S[1], S[2], S[3]);
  cp[1] = make_float4(S[4], S[5], S[6], S[7]);
}

// ---------------------------------------------------------------------------
// K2: NO compaction. Reads meta + order from global (launch boundary
// guarantees visibility). Prefix + verify + speculative finalize +
// last-arriving-wave fallback. 8-deep memory pipelines.
// ---------------------------------------------------------------------------
__global__ __launch_bounds__(256)
void verify_kernel(const float* __restrict__ feats, int B,
                   const float* __restrict__ chunksum, const int* __restrict__ order_g,
                   const int* __restrict__ cb_g, const int* __restrict__ cc_g,
                   const int* __restrict__ chb_g, const int* __restrict__ ncht_g,
                   int* __restrict__ done_g, int* __restrict__ fail_g,
                   float* __restrict__ gproto, float* __restrict__ p2s,
                   float* __restrict__ sps, int* __restrict__ nproto_g)
{
  __shared__ int   cb_s[NC], cc_s[NC], chb_s[NC];
  __shared__ int   nchtot_s;
  __shared__ float ls_proto[NLDS][ND];
  __shared__ int   ls_cnt[NP];
  __shared__ int   fblock;

  const int t = threadIdx.x, lane = t & 63, w = t >> 6;
  if (t < NC) { cb_s[t] = cb_g[t]; cc_s[t] = cc_g[t]; chb_s[t] = chb_g[t]; }
  if (t == 32) nchtot_s = ncht_g[0];
  if (t == 33) fblock = 0;
  __syncthreads();

  if (w >= WPB) return;
  const int gwid = blockIdx.x * WPB + w;
  if (gwid >= nchtot_s) return;

  int c = 0;
  while (c + 1 < NC && chb_s[c + 1] <= gwid) ++c;
  const int g = gwid - chb_s[c];
  const int cnt = cc_s[c], base = cb_s[c];
  const int nchc = (cnt + CH - 1) / CH;
  const int k0 = g * CH, k1 = min(k0 + CH, cnt);
  int myidx = (lane < CH && k0 + lane < cnt) ? order_g[base + k0 + lane] : 0;

  // ---- prefix over preceding windows of this class (ascending, 8-deep) ----
  float P[8] = {0, 0, 0, 0, 0, 0, 0, 0};
  {
    const float* cbase = chunksum + (size_t)chb_s[c] * ND + lane * 8;
    int j = 0;
    for (; j + 8 <= g; j += 8) {
      float4 A[8], Bv[8];
#pragma unroll
      for (int q = 0; q < 8; ++q) {
        const float4* pp = (const float4*)(cbase + (size_t)(j + q) * ND);
        A[q] = pp[0]; Bv[q] = pp[1];
      }
#pragma unroll
      for (int q = 0; q < 8; ++q) {
        P[0]+=A[q].x; P[1]+=A[q].y; P[2]+=A[q].z; P[3]+=A[q].w;
        P[4]+=Bv[q].x; P[5]+=Bv[q].y; P[6]+=Bv[q].z; P[7]+=Bv[q].w;
      }
    }
    for (; j < g; ++j) {
      const float4* pp = (const float4*)(cbase + (size_t)j * ND);
      float4 a = pp[0], b = pp[1];
      P[0]+=a.x; P[1]+=a.y; P[2]+=a.z; P[3]+=a.w;
      P[4]+=b.x; P[5]+=b.y; P[6]+=b.z; P[7]+=b.w;
    }
  }

  // ---- verify 16 samples (8-deep batch, 8 interleaved butterflies) ----
  int k = k0;
  for (; k + 8 <= k1; k += 8) {
    float4 A[8], Bv[8];
#pragma unroll
    for (int j = 0; j < 8; ++j) {
      int idx = __shfl(myidx, k + j - k0, 64);
      const float4* fp = (const float4*)(feats + (size_t)idx * ND + lane * 8);
      A[j] = fp[0]; Bv[j] = fp[1];
    }
    float part[8];
#pragma unroll
    for (int j = 0; j < 8; ++j) {
      int kk = k + j;
      float f[8] = {A[j].x, A[j].y, A[j].z, A[j].w, Bv[j].x, Bv[j].y, Bv[j].z, Bv[j].w};
      if (kk > 0) {
        float invk = 1.f / (float)kk;
        float p = 0.f;
#pragma unroll
        for (int e = 0; e < 8; ++e) { float d = f[e] - P[e] * invk + FEPS; p += d * d; }
        part[j] = p;
      } else part[j] = 0.f;
#pragma unroll
      for (int e = 0; e < 8; ++e) P[e] += f[e];
    }
#pragma unroll
    for (int m = 1; m < 64; m <<= 1) {
#pragma unroll
      for (int j = 0; j < 8; ++j) part[j] += __shfl_xor(part[j], m, 64);
    }
    if (lane == 0) {
#pragma unroll
      for (int j = 0; j < 8; ++j) {
        int kk = k + j;
        if (kk > 0 && !(part[j] < THR2)) atomicOr(&fail_g[c], 1);
      }
    }
  }
  for (; k < k1; ++k) {
    int idx = __shfl(myidx, k - k0, 64);
    const float4* fp = (const float4*)(feats + (size_t)idx * ND + lane * 8);
    float4 fa = fp[0], fb = fp[1];
    float f[8] = {fa.x, fa.y, fa.z, fa.w, fb.x, fb.y, fb.z, fb.w};
    if (k > 0) {
      float invk = 1.f / (float)k;
      float p = 0.f;
#pragma unroll
      for (int e = 0; e < 8; ++e) { float d = f[e] - P[e] * invk + FEPS; p += d * d; }
      float d2 = allredf(p);
      if (!(d2 < THR2) && lane == 0) atomicOr(&fail_g[c], 1);
    }
#pragma unroll
    for (int e = 0; e < 8; ++e) P[e] += f[e];
  }

  // ---- last window holds the full class sum: speculative finalize ----
  if (g == nchc - 1) {
    float invc = 1.f / (float)cnt;
    float p[8];
#pragma unroll
    for (int e = 0; e < 8; ++e) p[e] = P[e] * invc;
    float4* gp = (float4*)(gproto + (size_t)c * NP * ND + lane * 8);
    gp[0] = make_float4(p[0], p[1], p[2], p[3]);
    gp[1] = make_float4(p[4], p[5], p[6], p[7]);
    float P2p = 0.f, SPp = 0.f;
#pragma unroll
    for (int e = 0; e < 8; ++e) { P2p += p[e]*p[e]; SPp += p[e]; }
    float P2 = allredf(P2p), SP = allredf(SPp);
    if (lane == 0) { p2s[c*NP] = P2; sps[c*NP] = SP; nproto_g[c] = 1; }
  }

  // ---- last-arriving wave for class c: run fallback if speculation failed ----
  __threadfence();
  int old = 0;
  if (lane == 0) old = atomicAdd(&done_g[c], 1);
  old = __shfl(old, 0, 64);
  if (old != nchc - 1) return;
  __threadfence();
  int fv = 0;
  if (lane == 0) fv = atomicOr(&fail_g[c], 0);   // atomic load
  fv = __shfl(fv, 0, 64);
  if (!fv) return;

  if (lane == 0) { while (atomicCAS(&fblock, 0, 1) != 0) {} }  // block LDS lock

  // faithful sequential fallback (one wave; indices from global order)
  {
    float p0[8];
    int cnt0 = 0, n = 0;
    float fA[8], fB[8], fC[8];

    auto LOADF = [&](float (&buf)[8], int m) {
      int idx = order_g[base + m];
      const float4* fp = (const float4*)(feats + (size_t)idx * ND + lane * 8);
      float4 a = fp[0], b = fp[1];
      buf[0]=a.x; buf[1]=a.y; buf[2]=a.z; buf[3]=a.w;
      buf[4]=b.x; buf[5]=b.y; buf[6]=b.z; buf[7]=b.w;
    };
    auto STEP = [&](float (&f)[8]) {
      float best = 3.4e38f;
      int bidx = 0;
      if (n > 0) {
        float part = 0.f;
#pragma unroll
        for (int e = 0; e < 8; ++e) { float d = f[e] - p0[e] + FEPS; part += d * d; }
        best = allredf(part);
        for (int j = 1; j < n; ++j) {
          float pj[8];
          if (j <= NLDS) {
            const float4* pp = (const float4*)(&ls_proto[j-1][lane*8]);
            float4 a = pp[0], b = pp[1];
            pj[0]=a.x; pj[1]=a.y; pj[2]=a.z; pj[3]=a.w;
            pj[4]=b.x; pj[5]=b.y; pj[6]=b.z; pj[7]=b.w;
          } else {
            const float4* pp = (const float4*)(gproto + ((size_t)c*NP + j)*ND + lane*8);
            float4 a = pp[0], b = pp[1];
            pj[0]=a.x; pj[1]=a.y; pj[2]=a.z; pj[3]=a.w;
            pj[4]=b.x; pj[5]=b.y; pj[6]=b.z; pj[7]=b.w;
          }
          float part2 = 0.f;
#pragma unroll
          for (int e = 0; e < 8; ++e) { float d = f[e] - pj[e] + FEPS; part2 += d * d; }
          float tot = allredf(part2);
          if (tot < best) { best = tot; bidx = j; }
        }
      }
      if (n > 0 && best < THR2) {
        if (bidx == 0) {
          float cc = (float)cnt0, iv = 1.f / (cc + 1.f);
#pragma unroll
          for (int e = 0; e < 8; ++e) p0[e] = (p0[e]*cc + f[e]) * iv;
          cnt0++;
        } else {
          int ci = ls_cnt[bidx];
          float cc = (float)ci, iv = 1.f / (cc + 1.f);
          if (bidx <= NLDS) {
            float* row = &ls_proto[bidx-1][lane*8];
#pragma unroll
            for (int e = 0; e < 8; ++e) row[e] = (row[e]*cc + f[e]) * iv;
          } else {
            float* row = gproto + ((size_t)c*NP + bidx)*ND + lane*8;
#pragma unroll
            for (int e = 0; e < 8; ++e) row[e] = (row[e]*cc + f[e]) * iv;
          }
          if (lane == 0) ls_cnt[bidx] = ci + 1;
        }
      } else {
        int app = min(n, NP - 1);
        if (app == 0) {
#pragma unroll
          for (int e = 0; e < 8; ++e) p0[e] = f[e];
          cnt0 = 1;
        } else if (app <= NLDS) {
          float* row = &ls_proto[app-1][lane*8];
#pragma unroll
          for (int e = 0; e < 8; ++e) row[e] = f[e];
          if (lane == 0) ls_cnt[app] = 1;
        } else {
          float* row = gproto + ((size_t)c*NP + app)*ND + lane*8;
#pragma unroll
          for (int e = 0; e < 8; ++e) row[e] = f[e];
          if (lane == 0) ls_cnt[app] = 1;
        }
        n = min(n + 1, NP);
      }
    };

    if (cnt > 0) LOADF(fA, 0);
    if (cnt > 1) LOADF(fB, 1);
    if (cnt > 2) LOADF(fC, 2);
    int m = 0;
    while (m < cnt) {
      STEP(fA); ++m; if (m + 2 < cnt) LOADF(fA, m + 2);
      if (m >= cnt) break;
      STEP(fB); ++m; if (m + 2 < cnt) LOADF(fB, m + 2);
      if (m >= cnt) break;
      STEP(fC); ++m; if (m + 2 < cnt) LOADF(fC, m + 2);
    }

    for (int j = 0; j < n; ++j) {
      float pj[8];
      if (j == 0) {
#pragma unroll
        for (int e = 0; e < 8; ++e) pj[e] = p0[e];
      } else if (j <= NLDS) {
        const float4* pp = (const float4*)(&ls_proto[j-1][lane*8]);
        float4 a = pp[0], b = pp[1];
        pj[0]=a.x; pj[1]=a.y; pj[2]=a.z; pj[3]=a.w;
        pj[4]=b.x; pj[5]=b.y; pj[6]=b.z; pj[7]=b.w;
      } else {
        const float4* pp = (const float4*)(gproto + ((size_t)c*NP + j)*ND + lane*8);
        float4 a = pp[0], b = pp[1];
        pj[0]=a.x; pj[1]=a.y; pj[2]=a.z; pj[3]=a.w;
        pj[4]=b.x; pj[5]=b.y; pj[6]=b.z; pj[7]=b.w;
      }
      float4* gp = (float4*)(gproto + ((size_t)c*NP + j)*ND + lane*8);
      gp[0] = make_float4(pj[0], pj[1], pj[2], pj[3]);
      gp[1] = make_float4(pj[4], pj[5], pj[6], pj[7]);
      float P2p = 0.f, SPp = 0.f;
#pragma unroll
      for (int e = 0; e < 8; ++e) { P2p += pj[e]*pj[e]; SPp += pj[e]; }
      float P2 = allredf(P2p), SP = allredf(SPp);
      if (lane == 0) { p2s[c*NP + j] = P2; sps[c*NP + j] = SP; }
    }
    if (lane == 0) nproto_g[c] = n;
  }

  __threadfence_block();
  if (lane == 0) atomicExch(&fblock, 0);
}

// ---------------------------------------------------------------------------
// K3: loss. Fast path: protos staged in LDS (kills 164 MB of per-wave L2
// proto re-reads), 4 samples per wave with one 48-value batched butterfly.
// General path (fallback data) unchanged.
// ---------------------------------------------------------------------------
__global__ __launch_bounds__(256)
void loss_kernel(const float* __restrict__ feats, const int* __restrict__ labels, int B,
                 const float* __restrict__ gproto, const float* __restrict__ p2s,
                 const float* __restrict__ sps, const int* __restrict__ nproto_g,
                 float* __restrict__ out)
{
  __shared__ float lsp[NC][ND];          // 20 KB staged prototypes
  __shared__ float lp2[NC], lsv[NC];
  __shared__ float bsum[4];
  const int t = threadIdx.x;
  const int lane = t & 63;
  const int wid  = t >> 6;
  const int gw   = blockIdx.x * 4 + wid;
  const int nw   = gridDim.x * 4;

  int np[NC];
  bool fast = true;
#pragma unroll
  for (int cc = 0; cc < NC; ++cc) { np[cc] = nproto_g[cc]; fast &= (np[cc] == 1); }

  float acc = 0.f;
  if (fast) {
    // stage protos + scalars into LDS (coalesced float4)
    for (int i = t; i < NC * (ND / 4); i += 256) {
      int cc = i / (ND / 4), off = i % (ND / 4);
      ((float4*)&lsp[cc][0])[off] = ((const float4*)(gproto + (size_t)cc * NP * ND))[off];
    }
    if (t < NC) { lp2[t] = p2s[t * NP]; lsv[t] = sps[t * NP]; }
    __syncthreads();

    for (int b0 = gw * 4; b0 < B; b0 += nw * 4) {
      const int ns = min(4, B - b0);
      float f[32];                      // 4 samples x 8 dims (compile-time idx)
      int lab[4];
#pragma unroll
      for (int s = 0; s < 4; ++s) {
        int b = b0 + ((s < ns) ? s : 0);
        const float4* fp = (const float4*)(feats + (size_t)b * ND + lane * 8);
        float4 a4 = fp[0], b4 = fp[1];
        f[s*8+0]=a4.x; f[s*8+1]=a4.y; f[s*8+2]=a4.z; f[s*8+3]=a4.w;
        f[s*8+4]=b4.x; f[s*8+5]=b4.y; f[s*8+6]=b4.z; f[s*8+7]=b4.w;
        lab[s] = labels[b];
      }

      float v[48];                      // 4 samples x (10 dots + f2 + sf)
#pragma unroll
      for (int cc = 0; cc < NC; ++cc) {
        const float4* pp = (const float4*)(&lsp[cc][lane * 8]);
        float4 pa = pp[0], pb = pp[1];
        float p[8] = {pa.x, pa.y, pa.z, pa.w, pb.x, pb.y, pb.z, pb.w};
#pragma unroll
        for (int s = 0; s < 4; ++s) {
          float d = 0.f;
#pragma unroll
          for (int e = 0; e < 8; ++e) d += f[s*8+e] * p[e];
          v[s*12+cc] = d;
        }
      }
#pragma unroll
      for (int s = 0; s < 4; ++s) {
        float f2p = 0.f, sfp = 0.f;
#pragma unroll
        for (int e = 0; e < 8; ++e) { f2p += f[s*8+e]*f[s*8+e]; sfp += f[s*8+e]; }
        v[s*12+10] = f2p; v[s*12+11] = sfp;
      }
#pragma unroll
      for (int m = 1; m < 64; m <<= 1) {
#pragma unroll
        for (int q = 0; q < 48; ++q) v[q] += __shfl_xor(v[q], m, 64);
      }

#pragma unroll
      for (int s = 0; s < 4; ++s) {
        if (s >= ns) break;
        float f2 = v[s*12+10], sf = v[s*12+11];
        float one = 0.f, num = 0.f, pw = 0.f;
#pragma unroll
        for (int cc = 0; cc < NC; ++cc) {
          float d2 = f2 + lp2[cc] - 2.f*v[s*12+cc]
                   + 2.f*FEPS*(sf - lsv[cc]) + (float)ND*FEPS*FEPS;
          d2 = fmaxf(d2, 0.f);
          float e = expf(-GAMMA * d2);
          one += e;
          if (cc == lab[s]) num = e;
          float dmin = sqrtf(d2);
          float sign = (cc == lab[s]) ? 1.f : -1.f;
          float z = BCONST - (TAO - dmin) * sign;
          float gg = (z > 10.f) ? z : log1pf(expf(z));
          pw += gg;
        }
        float prob = 1e-6f + ((one > 0.f) ? num / one : one);
        acc += -logf(prob) + LAMBDA * pw;
      }
    }
  } else {
    for (int b = gw; b < B; b += nw) {
      const float4* fp = (const float4*)(feats + (size_t)b * ND + lane * 8);
      float4 a4 = fp[0], b4 = fp[1];
      float f[8] = {a4.x, a4.y, a4.z, a4.w, b4.x, b4.y, b4.z, b4.w};
      float f2p = 0.f, sfp = 0.f;
#pragma unroll
      for (int e = 0; e < 8; ++e) { f2p += f[e]*f[e]; sfp += f[e]; }
      float f2 = allredf(f2p);
      float sf = allredf(sfp);
      int lab = labels[b];
      float one = 0.f, num = 0.f, pw = 0.f;
      for (int cc = 0; cc < NC; ++cc) {
        int nn = np[cc];
        if (nn <= 0) continue;
        float sume = 0.f, bestd2 = 3.4e38f;
        for (int j = 0; j < nn; ++j) {
          const float4* pp = (const float4*)(gproto + ((size_t)cc*NP + j)*ND + lane*8);
          float4 pa = pp[0], pb = pp[1];
          float dp = f[0]*pa.x + f[1]*pa.y + f[2]*pa.z + f[3]*pa.w
                   + f[4]*pb.x + f[5]*pb.y + f[6]*pb.z + f[7]*pb.w;
          float dot = allredf(dp);
          float d2 = f2 + p2s[cc*NP + j] - 2.f*dot
                   + 2.f*FEPS*(sf - sps[cc*NP + j]) + (float)ND*FEPS*FEPS;
          d2 = fmaxf(d2, 0.f);
          sume  += expf(-GAMMA * d2);
          bestd2 = fminf(bestd2, d2);
        }
        one += sume;
        if (cc == lab) num = sume;
        float dmin = sqrtf(bestd2);
        float sign = (cc == lab) ? 1.f : -1.f;
        float z = BCONST - (TAO - dmin) * sign;
        float g = (z > 10.f) ? z : log1pf(expf(z));
        pw += g;
      }
      float prob = 1e-6f + ((one > 0.f) ? num / one : one);
      acc += -logf(prob) + LAMBDA * pw;
    }
  }

  if (lane == 0) bsum[wid] = acc;
  __syncthreads();
  if (t == 0) atomicAdd(out, bsum[0] + bsum[1] + bsum[2] + bsum[3]);
}

// ---------------------------------------------------------------------------
extern "C" void kernel_launch(void* const* d_in, const int* in_sizes, int n_in,
                              void* d_out, int out_size, void* d_ws, size_t ws_size,
                              hipStream_t stream) {
  const float* feats  = (const float*)d_in[0];
  const int*   labels = (const int*)d_in[1];
  int B = in_sizes[0] / ND;   // 8192
  const int maxwin = (B + CH - 1) / CH + NC;

  float* gproto   = (float*)d_ws;                          // NC*NP*ND
  float* p2s      = gproto + (size_t)NC * NP * ND;         // NC*NP
  float* sps      = p2s + NC * NP;                         // NC*NP
  float* chunksum = sps + NC * NP;                         // maxwin*ND
  int*   order_g  = (int*)(chunksum + (size_t)maxwin * ND);// B
  int*   cb_g     = order_g + B;                           // NC
  int*   cc_g     = cb_g + NC;                             // NC
  int*   chb_g    = cc_g + NC;                             // NC
  int*   ncht_g   = chb_g + NC;                            // 1
  int*   done_g   = ncht_g + 1;                            // NC
  int*   fail_g   = done_g + NC;                           // NC
  int*   nproto_g = fail_g + NC;                           // NC
  float* outf     = (float*)d_out;

  hipLaunchKernelGGL(sumc_kernel, dim3(NBLK), dim3(256), 0, stream,
                     feats, labels, B, chunksum, order_g, cb_g, cc_g, chb_g,
                     ncht_g, done_g, fail_g, nproto_g, outf);
  hipLaunchKernelGGL(verify_kernel, dim3(NBLK), dim3(256), 0, stream,
                     feats, B, chunksum, order_g, cb_g, cc_g, chb_g, ncht_g,
                     done_g, fail_g, gproto, p2s, sps, nproto_g);
  hipLaunchKernelGGL(loss_kernel, dim3(512), dim3(256), 0, stream,
                     feats, labels, B, gproto, p2s, sps, nproto_g, outf);
}